// Round 1
// baseline (449.055 us; speedup 1.0000x reference)
//
#include <hip/hip_runtime.h>
#include <math.h>

// ---------------- problem constants (from reference) ----------------
#define N_NODES 50000
#define N_EDGES 800000
#define ETOT    (N_EDGES + N_NODES)   // self-loops appended
#define NFEAT   128
#define NHID    16
#define HEADS   8
#define HD      (HEADS * NHID)        // 128
#define NCLASS  2
#define NEG     0.2f
#define NEG_BIG -3.402823466e38f

// =====================================================================
// K0: zero degree array (ws is poisoned 0xAA before every launch)
// =====================================================================
__global__ void k_zero(int* __restrict__ deg) {
    int i = blockIdx.x * blockDim.x + threadIdx.x;
    if (i < N_NODES) deg[i] = 0;
}

// =====================================================================
// K1: detect whether edge_index arrived as int64 (odd 32-bit words all 0)
//     or int32. Same work every call; graph-capture safe.
// =====================================================================
__global__ void k_detect(const unsigned int* __restrict__ ei, int* __restrict__ flag) {
    __shared__ int any;
    if (threadIdx.x == 0) any = 0;
    __syncthreads();
    unsigned v = ei[2 * threadIdx.x + 1];   // words 1,3,...,511
    if (v != 0u) any = 1;
    __syncthreads();
    if (threadIdx.x == 0) *flag = (any == 0) ? 1 : 0;  // 1 => int64
}

// =====================================================================
// K2: canonicalize edges (append self-loops) + degree histogram on dst
// =====================================================================
__global__ void k_build(const void* __restrict__ ei, const int* __restrict__ flag,
                        int* __restrict__ src, int* __restrict__ dst,
                        int* __restrict__ deg) {
    int e = blockIdx.x * blockDim.x + threadIdx.x;
    if (e >= ETOT) return;
    int s, d;
    if (e < N_EDGES) {
        if (*flag) {
            const long long* p = (const long long*)ei;
            s = (int)p[e];
            d = (int)p[N_EDGES + e];
        } else {
            const int* p = (const int*)ei;
            s = p[e];
            d = p[N_EDGES + e];
        }
    } else {
        s = e - N_EDGES;
        d = s;
    }
    src[e] = s;
    dst[e] = d;
    atomicAdd(&deg[d], 1);
}

// =====================================================================
// K3: single-block exclusive scan of deg -> row_ptr (and cursor copy)
// =====================================================================
__global__ __launch_bounds__(1024) void k_scan(const int* __restrict__ deg,
                                               int* __restrict__ row_ptr,
                                               int* __restrict__ cursor) {
    __shared__ int wsum[16];
    __shared__ int srun;
    const int tid  = threadIdx.x;          // 1024 threads
    const int lane = tid & 63;
    const int wid  = tid >> 6;
    if (tid == 0) srun = 0;
    __syncthreads();
    for (int base = 0; base < N_NODES; base += 1024) {
        int i = base + tid;
        int v = (i < N_NODES) ? deg[i] : 0;
        int orig = v;
        // inclusive wave scan
        #pragma unroll
        for (int off = 1; off < 64; off <<= 1) {
            int t = __shfl_up(v, off, 64);
            if (lane >= off) v += t;
        }
        if (lane == 63) wsum[wid] = v;
        __syncthreads();
        if (wid == 0) {
            int w = (lane < 16) ? wsum[lane] : 0;
            #pragma unroll
            for (int off = 1; off < 16; off <<= 1) {
                int t = __shfl_up(w, off, 64);
                if (lane >= off) w += t;
            }
            if (lane < 16) wsum[lane] = w;   // inclusive wave totals
        }
        __syncthreads();
        int waveoff = (wid > 0) ? wsum[wid - 1] : 0;
        int incl = v + waveoff;
        int run = srun;
        if (i < N_NODES) {
            int ex = run + incl - orig;      // exclusive
            row_ptr[i] = ex;
            cursor[i]  = ex;
        }
        __syncthreads();                     // everyone read srun
        if (tid == 1023) srun = run + incl;  // block total
        __syncthreads();
    }
    if (tid == 0) row_ptr[N_NODES] = srun;
}

// =====================================================================
// K4: scatter edges into CSR-by-dst (order within a segment irrelevant)
// =====================================================================
__global__ void k_scatter(const int* __restrict__ src, const int* __restrict__ dst,
                          int* __restrict__ cursor, int* __restrict__ csr_src) {
    int e = blockIdx.x * blockDim.x + threadIdx.x;
    if (e >= ETOT) return;
    int d = dst[e];
    int pos = atomicAdd(&cursor[d], 1);
    csr_src[pos] = src[e];
}

// =====================================================================
// K5: h1 = x @ W1  (f32, W1 in LDS)  + fused per-head attention dots
//     thread = output channel c (c = h*16 + cc), block = 128 threads
// =====================================================================
__global__ __launch_bounds__(128) void k_gemm1(
        const float* __restrict__ x, const float* __restrict__ W1,
        const float* __restrict__ as1, const float* __restrict__ ad1,
        float* __restrict__ h1, float* __restrict__ asrc1, float* __restrict__ adst1) {
    __shared__ float Wl[NFEAT * HD];   // 64 KB
    __shared__ float xrow[NFEAT];
    const int tid = threadIdx.x;
    {   // cooperative W1 load (float4)
        const float4* W4  = reinterpret_cast<const float4*>(W1);
        float4*       Wl4 = reinterpret_cast<float4*>(Wl);
        for (int i = tid; i < NFEAT * HD / 4; i += 128) Wl4[i] = W4[i];
    }
    const float a_s = as1[tid];   // att_src1 flat [h][cc] == [tid]
    const float a_d = ad1[tid];
    __syncthreads();
    for (int n = blockIdx.x; n < N_NODES; n += gridDim.x) {
        xrow[tid] = x[n * NFEAT + tid];
        __syncthreads();
        float acc = 0.f;
        #pragma unroll
        for (int k = 0; k < NFEAT; k += 4) {
            float4 xv = *reinterpret_cast<const float4*>(&xrow[k]);
            acc = fmaf(xv.x, Wl[(k + 0) * HD + tid], acc);
            acc = fmaf(xv.y, Wl[(k + 1) * HD + tid], acc);
            acc = fmaf(xv.z, Wl[(k + 2) * HD + tid], acc);
            acc = fmaf(xv.w, Wl[(k + 3) * HD + tid], acc);
        }
        h1[n * HD + tid] = acc;
        // per-head dot with att vectors: reduce within 16-lane groups
        float vs = acc * a_s, vd = acc * a_d;
        #pragma unroll
        for (int o = 1; o < 16; o <<= 1) {
            vs += __shfl_xor(vs, o, 16);
            vd += __shfl_xor(vd, o, 16);
        }
        if ((tid & 15) == 0) {
            asrc1[n * HEADS + (tid >> 4)] = vs;
            adst1[n * HEADS + (tid >> 4)] = vd;
        }
        __syncthreads();   // xrow reuse guard
    }
}

// =====================================================================
// K6: layer-1 aggregation, one block (128 thr) per node.
//     Online softmax per (head,channel)-thread; single pass over edges.
//     Epilogue: ELU, then fused layer-2 linear (128->2) + attention dots.
// =====================================================================
__global__ __launch_bounds__(128) void k_agg1(
        const int* __restrict__ row_ptr, const int* __restrict__ csr_src,
        const float* __restrict__ asrc1, const float* __restrict__ adst1,
        const float* __restrict__ h1, const float* __restrict__ bias1,
        const float* __restrict__ W2, const float* __restrict__ as2,
        const float* __restrict__ ad2,
        float* __restrict__ h2, float* __restrict__ asrc2, float* __restrict__ adst2) {
    const int n    = blockIdx.x;
    const int tid  = threadIdx.x;      // channel c = h*16+cc
    const int h    = tid >> 4;
    const int lane = tid & 63;
    const int wid  = tid >> 6;
    __shared__ int   slds[128];
    __shared__ float w0s[2], w1s[2];
    const float adst = adst1[n * HEADS + h];
    const int beg = row_ptr[n], end = row_ptr[n + 1];
    float m = NEG_BIG, den = 0.f, acc = 0.f;
    for (int base = beg; base < end; base += 128) {
        int cnt = min(128, end - base);
        __syncthreads();
        if (tid < cnt) slds[tid] = csr_src[base + tid];
        __syncthreads();
        for (int j = 0; j < cnt; j++) {
            int s = slds[j];
            float e = asrc1[s * HEADS + h] + adst;
            e = (e > 0.f) ? e : NEG * e;            // LeakyReLU
            float mn = fmaxf(m, e);
            float sc = __expf(m - mn);              // ==1 when max unchanged
            float p  = __expf(e - mn);
            den = den * sc + p;
            acc = acc * sc + p * h1[s * HD + tid];  // coalesced 512B gather
            m = mn;
        }
    }
    float hv = acc / den + bias1[tid];
    hv = (hv > 0.f) ? hv : (__expf(hv) - 1.f);      // ELU
    // fused layer-2 linear: h2[n,:] = hv-row @ W2 (128x2)
    float p0 = hv * W2[tid * NCLASS + 0];
    float p1 = hv * W2[tid * NCLASS + 1];
    #pragma unroll
    for (int o = 32; o > 0; o >>= 1) {
        p0 += __shfl_xor(p0, o, 64);
        p1 += __shfl_xor(p1, o, 64);
    }
    if (lane == 0) { w0s[wid] = p0; w1s[wid] = p1; }
    __syncthreads();
    if (tid == 0) {
        float h20 = w0s[0] + w0s[1];
        float h21 = w1s[0] + w1s[1];
        h2[n * 2 + 0] = h20;
        h2[n * 2 + 1] = h21;
        asrc2[n] = h20 * as2[0] + h21 * as2[1];
        adst2[n] = h20 * ad2[0] + h21 * ad2[1];
    }
}

// =====================================================================
// K7: layer-2 aggregation (1 head, 2 ch), one wave per node, fused
//     log_softmax. Lane-parallel edges + butterfly online-softmax merge.
// =====================================================================
__global__ __launch_bounds__(256) void k_agg2(
        const int* __restrict__ row_ptr, const int* __restrict__ csr_src,
        const float* __restrict__ asrc2, const float* __restrict__ adst2,
        const float* __restrict__ h2, const float* __restrict__ bias2,
        float* __restrict__ out) {
    const int lane = threadIdx.x & 63;
    const int n = blockIdx.x * 4 + (threadIdx.x >> 6);
    if (n >= N_NODES) return;
    const float adst = adst2[n];
    const int beg = row_ptr[n], end = row_ptr[n + 1];
    float m = NEG_BIG, den = 0.f, a0 = 0.f, a1 = 0.f;
    for (int i = beg + lane; i < end; i += 64) {
        int s = csr_src[i];
        float e = asrc2[s] + adst;
        e = (e > 0.f) ? e : NEG * e;
        float mn = fmaxf(m, e);
        float sc = __expf(m - mn);
        float p  = __expf(e - mn);
        float2 hv = *reinterpret_cast<const float2*>(&h2[s * 2]);
        den = den * sc + p;
        a0  = a0 * sc + p * hv.x;
        a1  = a1 * sc + p * hv.y;
        m = mn;
    }
    // butterfly merge of (m, den, a0, a1) online-softmax states
    #pragma unroll
    for (int off = 1; off < 64; off <<= 1) {
        float m2 = __shfl_xor(m,  off, 64);
        float d2 = __shfl_xor(den, off, 64);
        float b0 = __shfl_xor(a0, off, 64);
        float b1 = __shfl_xor(a1, off, 64);
        float mn = fmaxf(m, m2);
        float s1 = __expf(m  - mn);   // safe: -FLT_MAX-finite stays huge-neg -> 0
        float s2 = __expf(m2 - mn);
        den = den * s1 + d2 * s2;
        a0  = a0  * s1 + b0 * s2;
        a1  = a1  * s1 + b1 * s2;
        m = mn;
    }
    if (lane == 0) {
        float o0 = a0 / den + bias2[0];
        float o1 = a1 / den + bias2[1];
        float mx = fmaxf(o0, o1);
        float lse = mx + logf(__expf(o0 - mx) + __expf(o1 - mx));
        out[n * 2 + 0] = o0 - lse;
        out[n * 2 + 1] = o1 - lse;
    }
}

// =====================================================================
extern "C" void kernel_launch(void* const* d_in, const int* in_sizes, int n_in,
                              void* d_out, int out_size, void* d_ws, size_t ws_size,
                              hipStream_t stream) {
    const float* x   = (const float*)d_in[0];
    const void*  ei  = d_in[1];
    const float* W1  = (const float*)d_in[2];
    const float* as1 = (const float*)d_in[3];
    const float* ad1 = (const float*)d_in[4];
    const float* b1  = (const float*)d_in[5];
    const float* W2  = (const float*)d_in[6];
    const float* as2 = (const float*)d_in[7];
    const float* ad2 = (const float*)d_in[8];
    const float* b2  = (const float*)d_in[9];
    float* out = (float*)d_out;

    char* ws = (char*)d_ws;
    size_t off = 0;
    auto alloc = [&](size_t bytes) -> char* {
        char* p = ws + off;
        off += (bytes + 255) & ~size_t(255);
        return p;
    };
    int*   src     = (int*)alloc(ETOT * 4);
    int*   dst     = (int*)alloc(ETOT * 4);
    int*   deg     = (int*)alloc(N_NODES * 4);
    int*   row_ptr = (int*)alloc((N_NODES + 1) * 4);
    int*   cursor  = (int*)alloc(N_NODES * 4);
    int*   csr     = (int*)alloc(ETOT * 4);
    int*   flag    = (int*)alloc(16);
    float* h1      = (float*)alloc((size_t)N_NODES * HD * 4);
    float* asrc1   = (float*)alloc(N_NODES * HEADS * 4);
    float* adst1   = (float*)alloc(N_NODES * HEADS * 4);
    float* h2      = (float*)alloc(N_NODES * 2 * 4);
    float* asrc2   = (float*)alloc(N_NODES * 4);
    float* adst2   = (float*)alloc(N_NODES * 4);

    k_zero<<<(N_NODES + 255) / 256, 256, 0, stream>>>(deg);
    k_detect<<<1, 256, 0, stream>>>((const unsigned int*)ei, flag);
    k_build<<<(ETOT + 255) / 256, 256, 0, stream>>>(ei, flag, src, dst, deg);
    k_scan<<<1, 1024, 0, stream>>>(deg, row_ptr, cursor);
    k_scatter<<<(ETOT + 255) / 256, 256, 0, stream>>>(src, dst, cursor, csr);
    k_gemm1<<<512, 128, 0, stream>>>(x, W1, as1, ad1, h1, asrc1, adst1);
    k_agg1<<<N_NODES, 128, 0, stream>>>(row_ptr, csr, asrc1, adst1, h1, b1,
                                        W2, as2, ad2, h2, asrc2, adst2);
    k_agg2<<<N_NODES / 4, 256, 0, stream>>>(row_ptr, csr, asrc2, adst2, h2, b2, out);
}

// Round 2
// 350.422 us; speedup vs baseline: 1.2815x; 1.2815x over previous
//
#include <hip/hip_runtime.h>
#include <math.h>

// ---------------- problem constants (from reference) ----------------
#define N_NODES 50000
#define N_PAD   50048                 // padded to 64-row tiles (782 tiles)
#define N_EDGES 800000
#define ETOT    (N_EDGES + N_NODES)   // self-loops appended
#define NFEAT   128
#define NHID    16
#define HEADS   8
#define HD      (HEADS * NHID)        // 128
#define NCLASS  2
#define NEG     0.2f
#define NEG_BIG -3.402823466e38f

typedef short  bf16x8 __attribute__((ext_vector_type(8)));
typedef float  f32x4  __attribute__((ext_vector_type(4)));
typedef unsigned short ushort;

__device__ __forceinline__ ushort f2bf(float f) {   // RNE f32->bf16
    unsigned u = __float_as_uint(f);
    unsigned r = (u + 0x7fffu + ((u >> 16) & 1u)) >> 16;
    return (ushort)r;
}
__device__ __forceinline__ float bf2f(ushort u) {
    return __uint_as_float(((unsigned)u) << 16);
}

// =====================================================================
// K0: zero degree array (ws is poisoned 0xAA before every launch)
// =====================================================================
__global__ void k_zero(int* __restrict__ deg) {
    int i = blockIdx.x * blockDim.x + threadIdx.x;
    if (i < N_NODES) deg[i] = 0;
}

// =====================================================================
// K1: detect int64 vs int32 edge_index (odd 32-bit words all zero => i64)
// =====================================================================
__global__ void k_detect(const unsigned int* __restrict__ ei, int* __restrict__ flag) {
    __shared__ int any;
    if (threadIdx.x == 0) any = 0;
    __syncthreads();
    unsigned v = ei[2 * threadIdx.x + 1];
    if (v != 0u) any = 1;
    __syncthreads();
    if (threadIdx.x == 0) *flag = (any == 0) ? 1 : 0;
}

// =====================================================================
// K2: canonicalize edges (append self-loops) + degree histogram on dst
// =====================================================================
__global__ void k_build(const void* __restrict__ ei, const int* __restrict__ flag,
                        int* __restrict__ src, int* __restrict__ dst,
                        int* __restrict__ deg) {
    int e = blockIdx.x * blockDim.x + threadIdx.x;
    if (e >= ETOT) return;
    int s, d;
    if (e < N_EDGES) {
        if (*flag) {
            const long long* p = (const long long*)ei;
            s = (int)p[e];
            d = (int)p[N_EDGES + e];
        } else {
            const int* p = (const int*)ei;
            s = p[e];
            d = p[N_EDGES + e];
        }
    } else {
        s = e - N_EDGES;
        d = s;
    }
    src[e] = s;
    dst[e] = d;
    atomicAdd(&deg[d], 1);
}

// =====================================================================
// K3: single-block exclusive scan of deg -> row_ptr (and cursor copy)
// =====================================================================
__global__ __launch_bounds__(1024) void k_scan(const int* __restrict__ deg,
                                               int* __restrict__ row_ptr,
                                               int* __restrict__ cursor) {
    __shared__ int wsum[16];
    __shared__ int srun;
    const int tid  = threadIdx.x;
    const int lane = tid & 63;
    const int wid  = tid >> 6;
    if (tid == 0) srun = 0;
    __syncthreads();
    for (int base = 0; base < N_NODES; base += 1024) {
        int i = base + tid;
        int v = (i < N_NODES) ? deg[i] : 0;
        int orig = v;
        #pragma unroll
        for (int off = 1; off < 64; off <<= 1) {
            int t = __shfl_up(v, off, 64);
            if (lane >= off) v += t;
        }
        if (lane == 63) wsum[wid] = v;
        __syncthreads();
        if (wid == 0) {
            int w = (lane < 16) ? wsum[lane] : 0;
            #pragma unroll
            for (int off = 1; off < 16; off <<= 1) {
                int t = __shfl_up(w, off, 64);
                if (lane >= off) w += t;
            }
            if (lane < 16) wsum[lane] = w;
        }
        __syncthreads();
        int waveoff = (wid > 0) ? wsum[wid - 1] : 0;
        int incl = v + waveoff;
        int run = srun;
        if (i < N_NODES) {
            int ex = run + incl - orig;
            row_ptr[i] = ex;
            cursor[i]  = ex;
        }
        __syncthreads();
        if (tid == 1023) srun = run + incl;
        __syncthreads();
    }
    if (tid == 0) row_ptr[N_NODES] = srun;
}

// =====================================================================
// K4: scatter edges into CSR-by-dst (store src AND dst per position)
// =====================================================================
__global__ void k_scatter(const int* __restrict__ src, const int* __restrict__ dst,
                          int* __restrict__ cursor,
                          int* __restrict__ csr_src, int* __restrict__ csr_dst) {
    int e = blockIdx.x * blockDim.x + threadIdx.x;
    if (e >= ETOT) return;
    int d = dst[e];
    int pos = atomicAdd(&cursor[d], 1);
    csr_src[pos] = src[e];
    csr_dst[pos] = d;
}

// =====================================================================
// K5a: convert x (f32) -> xb (bf16), zero-padded to N_PAD rows
// =====================================================================
typedef ushort u16x8 __attribute__((ext_vector_type(8)));
__global__ void k_cvtx(const float* __restrict__ x, ushort* __restrict__ xb) {
    int idx = blockIdx.x * blockDim.x + threadIdx.x;   // chunk of 8 elems
    if (idx >= N_PAD * (NFEAT / 8)) return;
    int row = idx >> 4;
    int k8  = (idx & 15) << 3;
    u16x8 o;
    if (row < N_NODES) {
        const float* p = x + (size_t)row * NFEAT + k8;
        #pragma unroll
        for (int i = 0; i < 8; i++) o[i] = f2bf(p[i]);
    } else {
        #pragma unroll
        for (int i = 0; i < 8; i++) o[i] = 0;
    }
    *(u16x8*)(xb + (size_t)row * NFEAT + k8) = o;
}

// =====================================================================
// K5b: convert + transpose W1 [128(k) x 128(c)] -> W1t bf16 [c][k]
// =====================================================================
__global__ void k_cvtw(const float* __restrict__ W1, ushort* __restrict__ W1t) {
    int idx = blockIdx.x * blockDim.x + threadIdx.x;
    if (idx >= NFEAT * HD) return;
    int k = idx >> 7, c = idx & 127;
    W1t[c * NFEAT + k] = f2bf(W1[idx]);
}

// =====================================================================
// K6: MFMA GEMM  h1 = x @ W1  (bf16 in, f32 acc), 64x128 tile per block,
//     4 waves x (16 rows x 128 cols). Fused per-head attention dots from
//     the f32 accumulators (16-lane shuffle reduce). h1 stored as bf16.
//     LDS XOR-swizzle (G4): byte ^= (row&7)<<4 on both write and read.
// =====================================================================
__global__ __launch_bounds__(256) void k_gemm1(
        const ushort* __restrict__ xb, const ushort* __restrict__ W1t,
        const float* __restrict__ as1, const float* __restrict__ ad1,
        ushort* __restrict__ h1b, float* __restrict__ asrc1, float* __restrict__ adst1) {
    __shared__ char Al[64 * 256];    // 16 KB: A tile, 256 B/row (swizzled)
    __shared__ char Wl[128 * 256];   // 32 KB: Wt,     256 B/row (swizzled)
    const int tid = threadIdx.x;
    const int l = tid & 63, w = tid >> 6;
    // stage W1t: 2048 16B-chunks, 8 per thread
    #pragma unroll
    for (int it = 0; it < 8; ++it) {
        int chunk = it * 256 + tid;
        int row = chunk >> 4, koff = (chunk & 15) << 4;
        int a = (row * 256 + koff) ^ ((row & 7) << 4);
        *(float4*)(Wl + a) = *(const float4*)((const char*)W1t + row * 256 + koff);
    }
    const int tile0 = blockIdx.x * 64;
    // stage A: 1024 16B-chunks, 4 per thread
    #pragma unroll
    for (int it = 0; it < 4; ++it) {
        int chunk = it * 256 + tid;
        int row = chunk >> 4, koff = (chunk & 15) << 4;
        int a = (row * 256 + koff) ^ ((row & 7) << 4);
        *(float4*)(Al + a) =
            *(const float4*)((const char*)xb + (size_t)(tile0 + row) * 256 + koff);
    }
    __syncthreads();
    f32x4 acc[8];
    #pragma unroll
    for (int i = 0; i < 8; i++) acc[i] = (f32x4){0.f, 0.f, 0.f, 0.f};
    #pragma unroll
    for (int kk = 0; kk < 4; ++kk) {                 // K step = 32 bf16 = 64 B
        const int arow = w * 16 + (l & 15);
        const int abyte = (arow * 256 + kk * 64 + ((l >> 4) << 4)) ^ ((arow & 7) << 4);
        bf16x8 af = *(const bf16x8*)(Al + abyte);
        #pragma unroll
        for (int nb = 0; nb < 8; ++nb) {
            const int bcol = nb * 16 + (l & 15);
            const int bbyte = (bcol * 256 + kk * 64 + ((l >> 4) << 4)) ^ ((bcol & 7) << 4);
            bf16x8 bfm = *(const bf16x8*)(Wl + bbyte);
            acc[nb] = __builtin_amdgcn_mfma_f32_16x16x32_bf16(af, bfm, acc[nb], 0, 0, 0);
        }
    }
    // per-head attention vectors: head == nb (16 cols per head)
    float asv[8], adv[8];
    #pragma unroll
    for (int nb = 0; nb < 8; nb++) {
        asv[nb] = as1[nb * 16 + (l & 15)];
        adv[nb] = ad1[nb * 16 + (l & 15)];
    }
    // D layout: col = nb*16 + (l&15), row = w*16 + (l>>4)*4 + i
    #pragma unroll
    for (int nb = 0; nb < 8; nb++) {
        #pragma unroll
        for (int i = 0; i < 4; i++) {
            const int row = tile0 + w * 16 + ((l >> 4) << 2) + i;
            const float v = acc[nb][i];
            h1b[(size_t)row * HD + nb * 16 + (l & 15)] = f2bf(v);  // padded, safe
            float ps = v * asv[nb], pd = v * adv[nb];
            #pragma unroll
            for (int off = 1; off < 16; off <<= 1) {
                ps += __shfl_xor(ps, off, 16);
                pd += __shfl_xor(pd, off, 16);
            }
            if ((l & 15) == 0 && row < N_NODES) {
                asrc1[row * HEADS + nb] = ps;
                adst1[row * HEADS + nb] = pd;
            }
        }
    }
}

// =====================================================================
// K7: per-(node,head) softmax max + denom. One wave per node:
//     lane = eslot*8 + h; online per-lane, butterfly merge over eslots.
// =====================================================================
__global__ __launch_bounds__(256) void k_mden(
        const int* __restrict__ row_ptr, const int* __restrict__ csr_src,
        const float* __restrict__ asrc1, const float* __restrict__ adst1,
        float* __restrict__ m_out, float* __restrict__ invden) {
    const int lane = threadIdx.x & 63;
    const int n = blockIdx.x * 4 + (threadIdx.x >> 6);
    if (n >= N_NODES) return;
    const int es = lane >> 3, h = lane & 7;
    const float adst = adst1[n * HEADS + h];
    const int beg = row_ptr[n], end = row_ptr[n + 1];
    float m = NEG_BIG, den = 0.f;
    for (int j = beg + es; j < end; j += 8) {
        int s = csr_src[j];
        float e = asrc1[s * HEADS + h] + adst;
        e = (e > 0.f) ? e : NEG * e;
        float mn = fmaxf(m, e);
        den = den * __expf(m - mn) + __expf(e - mn);
        m = mn;
    }
    #pragma unroll
    for (int off = 8; off < 64; off <<= 1) {
        float m2 = __shfl_xor(m, off, 64);
        float d2 = __shfl_xor(den, off, 64);
        float mn = fmaxf(m, m2);
        den = den * __expf(m - mn) + d2 * __expf(m2 - mn);
        m = mn;
    }
    if (es == 0) {
        m_out[n * HEADS + h]  = m;
        invden[n * HEADS + h] = 1.f / den;
    }
}

// =====================================================================
// K8: edge-parallel softmax weights  w[i][h] = exp(e - m[d]) * invden[d]
// =====================================================================
__global__ __launch_bounds__(256) void k_edgew(
        const int* __restrict__ csr_src, const int* __restrict__ csr_dst,
        const float* __restrict__ asrc1, const float* __restrict__ adst1,
        const float* __restrict__ m_in, const float* __restrict__ invden,
        float* __restrict__ w_csr) {
    int i = blockIdx.x * blockDim.x + threadIdx.x;
    if (i >= ETOT) return;
    int s = csr_src[i], d = csr_dst[i];
    const float4* As = (const float4*)(asrc1 + s * HEADS);
    const float4* Ad = (const float4*)(adst1 + d * HEADS);
    const float4* Mm = (const float4*)(m_in + d * HEADS);
    const float4* Iv = (const float4*)(invden + d * HEADS);
    float4* Wo = (float4*)(w_csr + (size_t)i * HEADS);
    #pragma unroll
    for (int q = 0; q < 2; q++) {
        float4 a = As[q], b = Ad[q], mm = Mm[q], iv = Iv[q], o;
        float e;
        e = a.x + b.x; e = (e > 0.f) ? e : NEG * e; o.x = __expf(e - mm.x) * iv.x;
        e = a.y + b.y; e = (e > 0.f) ? e : NEG * e; o.y = __expf(e - mm.y) * iv.y;
        e = a.z + b.z; e = (e > 0.f) ? e : NEG * e; o.z = __expf(e - mm.z) * iv.z;
        e = a.w + b.w; e = (e > 0.f) ? e : NEG * e; o.w = __expf(e - mm.w) * iv.w;
        Wo[q] = o;
    }
}

// =====================================================================
// K9: layer-1 aggregation: pure weighted gather-sum (1 FMA/edge/thread).
//     Epilogue: bias + ELU + fused layer-2 linear (128->2) + att2 dots.
// =====================================================================
__global__ __launch_bounds__(128) void k_agg1(
        const int* __restrict__ row_ptr, const int* __restrict__ csr_src,
        const float* __restrict__ w_csr, const ushort* __restrict__ h1b,
        const float* __restrict__ bias1,
        const float* __restrict__ W2, const float* __restrict__ as2,
        const float* __restrict__ ad2,
        float* __restrict__ h2, float* __restrict__ asrc2, float* __restrict__ adst2) {
    const int n    = blockIdx.x;
    const int tid  = threadIdx.x;      // channel c = h*16+cc
    const int h    = tid >> 4;
    const int lane = tid & 63;
    const int wid  = tid >> 6;
    __shared__ int   slds[128];
    __shared__ float wlds[128 * 8];
    __shared__ float w0s[2], w1s[2];
    const int beg = row_ptr[n], end = row_ptr[n + 1];
    float acc = 0.f;
    for (int base = beg; base < end; base += 128) {
        int cnt = min(128, end - base);
        __syncthreads();
        if (tid < cnt) {
            slds[tid] = csr_src[base + tid];
            const float4* wp = (const float4*)(w_csr + (size_t)(base + tid) * HEADS);
            float4* wl = (float4*)(wlds + tid * 8);
            wl[0] = wp[0];
            wl[1] = wp[1];
        }
        __syncthreads();
        for (int j = 0; j < cnt; j++) {
            int s = slds[j];
            acc = fmaf(wlds[j * 8 + h], bf2f(h1b[(size_t)s * HD + tid]), acc);
        }
    }
    float hv = acc + bias1[tid];
    hv = (hv > 0.f) ? hv : (__expf(hv) - 1.f);      // ELU
    float p0 = hv * W2[tid * NCLASS + 0];
    float p1 = hv * W2[tid * NCLASS + 1];
    #pragma unroll
    for (int o = 32; o > 0; o >>= 1) {
        p0 += __shfl_xor(p0, o, 64);
        p1 += __shfl_xor(p1, o, 64);
    }
    if (lane == 0) { w0s[wid] = p0; w1s[wid] = p1; }
    __syncthreads();
    if (tid == 0) {
        float h20 = w0s[0] + w0s[1];
        float h21 = w1s[0] + w1s[1];
        h2[n * 2 + 0] = h20;
        h2[n * 2 + 1] = h21;
        asrc2[n] = h20 * as2[0] + h21 * as2[1];
        adst2[n] = h20 * ad2[0] + h21 * ad2[1];
    }
}

// =====================================================================
// K10: layer-2 aggregation + fused log_softmax (1 head, 2 channels).
// =====================================================================
__global__ __launch_bounds__(256) void k_agg2(
        const int* __restrict__ row_ptr, const int* __restrict__ csr_src,
        const float* __restrict__ asrc2, const float* __restrict__ adst2,
        const float* __restrict__ h2, const float* __restrict__ bias2,
        float* __restrict__ out) {
    const int lane = threadIdx.x & 63;
    const int n = blockIdx.x * 4 + (threadIdx.x >> 6);
    if (n >= N_NODES) return;
    const float adst = adst2[n];
    const int beg = row_ptr[n], end = row_ptr[n + 1];
    float m = NEG_BIG, den = 0.f, a0 = 0.f, a1 = 0.f;
    for (int i = beg + lane; i < end; i += 64) {
        int s = csr_src[i];
        float e = asrc2[s] + adst;
        e = (e > 0.f) ? e : NEG * e;
        float mn = fmaxf(m, e);
        float sc = __expf(m - mn);
        float p  = __expf(e - mn);
        float2 hv = *reinterpret_cast<const float2*>(&h2[s * 2]);
        den = den * sc + p;
        a0  = a0 * sc + p * hv.x;
        a1  = a1 * sc + p * hv.y;
        m = mn;
    }
    #pragma unroll
    for (int off = 1; off < 64; off <<= 1) {
        float m2 = __shfl_xor(m,  off, 64);
        float d2 = __shfl_xor(den, off, 64);
        float b0 = __shfl_xor(a0, off, 64);
        float b1 = __shfl_xor(a1, off, 64);
        float mn = fmaxf(m, m2);
        float s1 = __expf(m  - mn);
        float s2 = __expf(m2 - mn);
        den = den * s1 + d2 * s2;
        a0  = a0  * s1 + b0 * s2;
        a1  = a1  * s1 + b1 * s2;
        m = mn;
    }
    if (lane == 0) {
        float o0 = a0 / den + bias2[0];
        float o1 = a1 / den + bias2[1];
        float mx = fmaxf(o0, o1);
        float lse = mx + logf(__expf(o0 - mx) + __expf(o1 - mx));
        out[n * 2 + 0] = o0 - lse;
        out[n * 2 + 1] = o1 - lse;
    }
}

// =====================================================================
extern "C" void kernel_launch(void* const* d_in, const int* in_sizes, int n_in,
                              void* d_out, int out_size, void* d_ws, size_t ws_size,
                              hipStream_t stream) {
    const float* x   = (const float*)d_in[0];
    const void*  ei  = d_in[1];
    const float* W1  = (const float*)d_in[2];
    const float* as1 = (const float*)d_in[3];
    const float* ad1 = (const float*)d_in[4];
    const float* b1  = (const float*)d_in[5];
    const float* W2  = (const float*)d_in[6];
    const float* as2 = (const float*)d_in[7];
    const float* ad2 = (const float*)d_in[8];
    const float* b2  = (const float*)d_in[9];
    float* out = (float*)d_out;

    char* ws = (char*)d_ws;
    size_t off = 0;
    auto alloc = [&](size_t bytes) -> char* {
        char* p = ws + off;
        off += (bytes + 255) & ~size_t(255);
        return p;
    };
    int*    src     = (int*)alloc(ETOT * 4);
    int*    dst     = (int*)alloc(ETOT * 4);
    int*    deg     = (int*)alloc(N_NODES * 4);
    int*    row_ptr = (int*)alloc((N_NODES + 1) * 4);
    int*    cursor  = (int*)alloc(N_NODES * 4);
    int*    csr     = (int*)alloc(ETOT * 4);
    int*    csrd    = (int*)alloc(ETOT * 4);
    int*    flag    = (int*)alloc(16);
    ushort* xb      = (ushort*)alloc((size_t)N_PAD * NFEAT * 2);
    ushort* W1t     = (ushort*)alloc(NFEAT * HD * 2);
    ushort* h1b     = (ushort*)alloc((size_t)N_PAD * HD * 2);
    float*  asrc1   = (float*)alloc((size_t)N_NODES * HEADS * 4);
    float*  adst1   = (float*)alloc((size_t)N_NODES * HEADS * 4);
    float*  m_buf   = (float*)alloc((size_t)N_NODES * HEADS * 4);
    float*  invden  = (float*)alloc((size_t)N_NODES * HEADS * 4);
    float*  w_csr   = (float*)alloc((size_t)ETOT * HEADS * 4);
    float*  h2      = (float*)alloc(N_NODES * 2 * 4);
    float*  asrc2   = (float*)alloc(N_NODES * 4);
    float*  adst2   = (float*)alloc(N_NODES * 4);

    k_zero<<<(N_NODES + 255) / 256, 256, 0, stream>>>(deg);
    k_detect<<<1, 256, 0, stream>>>((const unsigned int*)ei, flag);
    k_build<<<(ETOT + 255) / 256, 256, 0, stream>>>(ei, flag, src, dst, deg);
    k_scan<<<1, 1024, 0, stream>>>(deg, row_ptr, cursor);
    k_scatter<<<(ETOT + 255) / 256, 256, 0, stream>>>(src, dst, cursor, csr, csrd);
    k_cvtx<<<(N_PAD * (NFEAT / 8) + 255) / 256, 256, 0, stream>>>(x, xb);
    k_cvtw<<<(NFEAT * HD + 255) / 256, 256, 0, stream>>>(W1, W1t);
    k_gemm1<<<N_PAD / 64, 256, 0, stream>>>(xb, W1t, as1, ad1, h1b, asrc1, adst1);
    k_mden<<<(N_NODES + 3) / 4, 256, 0, stream>>>(row_ptr, csr, asrc1, adst1,
                                                  m_buf, invden);
    k_edgew<<<(ETOT + 255) / 256, 256, 0, stream>>>(csr, csrd, asrc1, adst1,
                                                    m_buf, invden, w_csr);
    k_agg1<<<N_NODES, 128, 0, stream>>>(row_ptr, csr, w_csr, h1b, b1,
                                        W2, as2, ad2, h2, asrc2, adst2);
    k_agg2<<<(N_NODES + 3) / 4, 256, 0, stream>>>(row_ptr, csr, asrc2, adst2, h2, b2, out);
}